// Round 11
// baseline (280.925 us; speedup 1.0000x reference)
//
#include <hip/hip_runtime.h>
#include <hip/hip_fp16.h>

#define THREADS 256
#define HTHREADS 512
#define NB 256           // nodes per bucket
#define KMAX 400         // >= ceil(N/NB)=391
#define NCHUNK 1024      // edge chunks for bucket sort (4 blocks/CU)

struct alignas(8) Half4 { __half2 a, b; };

// ---------------------------------------------------------------------------
// detect -> hist -> colscan (wave/bucket) -> basescan -> passB -> passC ->
// gemm1 (reg-blocked, writes SPLIT g1a/g1b) ->
// agg1s x2 (feature-sliced gather, 6.4 MB footprint each, writes unified h1)
// -> gemm2 (reads h1, writes SPLIT g2a/g2b) ->
// agg2s x2 (3.2 MB footprint each, writes out slices)
//
// R10 lesson: agg gathers hit an MSHR-concurrency x miss-latency wall at
// ~3.5 TB/s (ILP 8->16 null; FETCH=72% of logical = L2 hit only 28% since
// g1=12.8MB >> 4MB/XCD L2). Fix = cut footprint per kernel below L2:
// feature-split slices. Same bytes, same math; misses become L2 hits.
// packed edge = (src << 8) | (dst & 255); bucket = dst >> 8
// ---------------------------------------------------------------------------

__global__ void k_detect(const int* __restrict__ e32, int* __restrict__ flag) {
    if (blockIdx.x == 0 && threadIdx.x == 0) {
        int st = 2;
        for (int i = 0; i < 64; ++i)
            if (e32[2 * i + 1] != 0) { st = 1; break; }
        *flag = st;
    }
}

__global__ __launch_bounds__(HTHREADS) void k_hist(const int* __restrict__ eidx,
                                                   const int* __restrict__ flag,
                                                   int E, int C, int K,
                                                   int* __restrict__ H) {
    __shared__ int hl[KMAX];
    int st = *flag;
    for (int i = threadIdx.x; i < K; i += HTHREADS) hl[i] = 0;
    __syncthreads();
    int s0 = blockIdx.x * C;
    int s1 = min(s0 + C, E);
    for (int e = s0 + threadIdx.x; e < s1; e += HTHREADS) {
        int d = eidx[(size_t)(E + e) * st];
        atomicAdd(&hl[d >> 8], 1);
    }
    __syncthreads();
    for (int i = threadIdx.x; i < K; i += HTHREADS)
        H[(size_t)blockIdx.x * K + i] = hl[i];
}

// wave per bucket: exclusive prefix of H[c][b] over c, 64 chunks/iteration
__global__ __launch_bounds__(THREADS) void k_colscan(int* __restrict__ H,
                                                     int* __restrict__ btot,
                                                     int K, int nchunk) {
    int b = (blockIdx.x * THREADS + threadIdx.x) >> 6;
    if (b >= K) return;
    int lane = threadIdx.x & 63;
    int run = 0;
    for (int i = 0; i < nchunk; i += 64) {
        int c = i + lane;
        int v = H[(size_t)c * K + b];
        int xs = v;
#pragma unroll
        for (int off = 1; off < 64; off <<= 1) {
            int t = __shfl_up(xs, off, 64);
            if (lane >= off) xs += t;
        }
        H[(size_t)c * K + b] = run + (xs - v);
        run += __shfl(xs, 63, 64);
    }
    if (lane == 0) btot[b] = run;
}

// exclusive scan of K<=2048 bucket totals, single block
__global__ __launch_bounds__(1024) void k_basescan(const int* __restrict__ btot,
                                                   int* __restrict__ base, int K) {
    __shared__ int s0[2048], s1[2048];
    int t = threadIdx.x;
    for (int i = t; i < 2048; i += 1024) s0[i] = (i < K) ? btot[i] : 0;
    __syncthreads();
    int* src = s0; int* dst = s1;
    for (int off = 1; off < 2048; off <<= 1) {
        for (int i = t; i < 2048; i += 1024)
            dst[i] = src[i] + (i >= off ? src[i - off] : 0);
        __syncthreads();
        int* tmp = src; src = dst; dst = tmp;
    }
    for (int i = t; i < 2048; i += 1024)
        if (i < K) base[i] = (i == 0) ? 0 : src[i - 1];
    if (t == 0) base[K] = src[K - 1];
}

__global__ __launch_bounds__(HTHREADS) void k_passB(const int* __restrict__ eidx,
                                                    const int* __restrict__ flag,
                                                    int E, int C, int K,
                                                    const int* __restrict__ H,
                                                    const int* __restrict__ base,
                                                    unsigned int* __restrict__ packed) {
    __shared__ int cur[KMAX];
    int st = *flag;
    for (int i = threadIdx.x; i < K; i += HTHREADS)
        cur[i] = base[i] + H[(size_t)blockIdx.x * K + i];
    __syncthreads();
    int s0 = blockIdx.x * C;
    int s1 = min(s0 + C, E);
    for (int e = s0 + threadIdx.x; e < s1; e += HTHREADS) {
        int s = eidx[(size_t)e * st];
        int d = eidx[(size_t)(E + e) * st];
        int pos = atomicAdd(&cur[d >> 8], 1);
        packed[pos] = ((unsigned)s << 8) | (unsigned)(d & 255);
    }
}

// per-bucket counting sort: packed -> csr (src by node), rowptr, dinv
__global__ __launch_bounds__(NB) void k_passC(const unsigned int* __restrict__ pk,
                                              const int* __restrict__ base,
                                              int K, int N,
                                              int* __restrict__ csr,
                                              int* __restrict__ rowptr,
                                              float* __restrict__ dinv) {
    __shared__ int cnt[NB];
    __shared__ int scn[NB];
    __shared__ int cur[NB];
    int b = blockIdx.x;
    int b0 = base[b], b1e = base[b + 1];
    int t = threadIdx.x;
    cnt[t] = 0;
    __syncthreads();
    for (int e = b0 + t; e < b1e; e += NB)
        atomicAdd(&cnt[pk[e] & 255u], 1);
    __syncthreads();
    int val = cnt[t];
    scn[t] = val;
    __syncthreads();
    for (int off = 1; off < NB; off <<= 1) {
        int tmp = (t >= off) ? scn[t - off] : 0;
        __syncthreads();
        scn[t] += tmp;
        __syncthreads();
    }
    int excl = b0 + scn[t] - val;
    cur[t] = excl;
    int v = b * NB + t;
    if (v < N) {
        rowptr[v] = excl;
        dinv[v] = rsqrtf((float)val + 1.0f);
    }
    if (b == K - 1 && t == 0) rowptr[N] = b1e;
    __syncthreads();
    for (int e = b0 + t; e < b1e; e += NB) {
        unsigned p = pk[e];
        int pos = atomicAdd(&cur[p & 255u], 1);
        csr[pos] = (int)(p >> 8);
    }
}

// reg-blocked GEMM1: 64-row tile, 4x4 per thread; writes split g1a/g1b
__global__ __launch_bounds__(THREADS) void k_gemm1(const float* __restrict__ x,
                                                   const float* __restrict__ W1,
                                                   const float* __restrict__ dinv,
                                                   __half* __restrict__ g1a,
                                                   __half* __restrict__ g1b, int N) {
    __shared__ float xT[128 * 65];
    __shared__ float Wl[128 * 64];
    for (int i = threadIdx.x; i < 128 * 64; i += THREADS) Wl[i] = W1[i];
    int row0 = blockIdx.x * 64;
    int kq = threadIdx.x & 31;
    int rr = threadIdx.x >> 5;
#pragma unroll
    for (int it = 0; it < 8; ++it) {
        int r = rr + it * 8;
        int gr = row0 + r;
        float4 xv = make_float4(0.f, 0.f, 0.f, 0.f);
        if (gr < N) xv = *(const float4*)(x + (size_t)gr * 128 + kq * 4);
        xT[(4 * kq + 0) * 65 + r] = xv.x;
        xT[(4 * kq + 1) * 65 + r] = xv.y;
        xT[(4 * kq + 2) * 65 + r] = xv.z;
        xT[(4 * kq + 3) * 65 + r] = xv.w;
    }
    __syncthreads();
    int tx = threadIdx.x & 15;
    int ty = threadIdx.x >> 4;
    float acc[4][4] = {};
#pragma unroll 4
    for (int k = 0; k < 128; ++k) {
        float4 a = *(const float4*)&xT[k * 65 + ty * 4];
        float4 b = *(const float4*)&Wl[k * 64 + tx * 4];
        acc[0][0] = fmaf(a.x, b.x, acc[0][0]);
        acc[0][1] = fmaf(a.x, b.y, acc[0][1]);
        acc[0][2] = fmaf(a.x, b.z, acc[0][2]);
        acc[0][3] = fmaf(a.x, b.w, acc[0][3]);
        acc[1][0] = fmaf(a.y, b.x, acc[1][0]);
        acc[1][1] = fmaf(a.y, b.y, acc[1][1]);
        acc[1][2] = fmaf(a.y, b.z, acc[1][2]);
        acc[1][3] = fmaf(a.y, b.w, acc[1][3]);
        acc[2][0] = fmaf(a.z, b.x, acc[2][0]);
        acc[2][1] = fmaf(a.z, b.y, acc[2][1]);
        acc[2][2] = fmaf(a.z, b.z, acc[2][2]);
        acc[2][3] = fmaf(a.z, b.w, acc[2][3]);
        acc[3][0] = fmaf(a.w, b.x, acc[3][0]);
        acc[3][1] = fmaf(a.w, b.y, acc[3][1]);
        acc[3][2] = fmaf(a.w, b.z, acc[3][2]);
        acc[3][3] = fmaf(a.w, b.w, acc[3][3]);
    }
    __half* dst = (tx < 8) ? g1a : g1b;
    int cq = (tx & 7) * 4;
#pragma unroll
    for (int i = 0; i < 4; ++i) {
        int gr = row0 + ty * 4 + i;
        if (gr < N) {
            float dr = dinv[gr];
            Half4 o;
            o.a = __floats2half2_rn(acc[i][0] * dr, acc[i][1] * dr);
            o.b = __floats2half2_rn(acc[i][2] * dr, acc[i][3] * dr);
            *(Half4*)(dst + (size_t)gr * 32 + cq) = o;
        }
    }
}

// feature-sliced agg layer1: 16 lanes/node, gs = one 6.4 MB slice (N x 16 half2),
// h1s pre-offset into unified h1 (row stride 32 half2); b1s pre-offset bias.
__global__ __launch_bounds__(THREADS) void k_agg1s(const int* __restrict__ rowptr,
                                                   const int* __restrict__ csr,
                                                   const __half2* __restrict__ gs,
                                                   const float* __restrict__ dinv,
                                                   const float* __restrict__ b1s,
                                                   __half2* __restrict__ h1s, int N) {
    int v = (blockIdx.x * THREADS + threadIdx.x) >> 4;
    if (v >= N) return;
    int f = threadIdx.x & 15;
    int beg = rowptr[v], end = rowptr[v + 1];
    float2 s = __half22float2(gs[(size_t)v * 16 + f]);
    float sx = s.x, sy = s.y;
    int j = beg;
    for (; j + 16 <= end; j += 16) {
        int idx[16];
#pragma unroll
        for (int u = 0; u < 16; ++u) idx[u] = csr[j + u];
        __half2 a[16];
#pragma unroll
        for (int u = 0; u < 16; ++u) a[u] = gs[(size_t)idx[u] * 16 + f];
        float tx = 0.f, ty = 0.f;
#pragma unroll
        for (int u = 0; u < 16; ++u) {
            float2 fa = __half22float2(a[u]);
            tx += fa.x; ty += fa.y;
        }
        sx += tx; sy += ty;
    }
    if (j + 8 <= end) {
        int idx[8];
#pragma unroll
        for (int u = 0; u < 8; ++u) idx[u] = csr[j + u];
        __half2 a[8];
#pragma unroll
        for (int u = 0; u < 8; ++u) a[u] = gs[(size_t)idx[u] * 16 + f];
#pragma unroll
        for (int u = 0; u < 8; ++u) {
            float2 fa = __half22float2(a[u]);
            sx += fa.x; sy += fa.y;
        }
        j += 8;
    }
    for (; j < end; ++j) {
        float2 a = __half22float2(gs[(size_t)csr[j] * 16 + f]);
        sx += a.x; sy += a.y;
    }
    float dr = dinv[v];
    float h0 = fmaxf(fmaf(dr, sx, b1s[2 * f + 0]), 0.0f);
    float h1v = fmaxf(fmaf(dr, sy, b1s[2 * f + 1]), 0.0f);
    h1s[(size_t)v * 32 + f] = __floats2half2_rn(h0, h1v);
}

// reg-blocked GEMM2: reads unified h1; writes split g2a/g2b
__global__ __launch_bounds__(THREADS) void k_gemm2(const __half* __restrict__ h1,
                                                   const float* __restrict__ W2,
                                                   const float* __restrict__ dinv,
                                                   __half* __restrict__ g2a,
                                                   __half* __restrict__ g2b, int N) {
    __shared__ float hT[64 * 129];
    __shared__ float Wl[64 * 32];
    for (int i = threadIdx.x; i < 64 * 32; i += THREADS) Wl[i] = W2[i];
    int row0 = blockIdx.x * 128;
    int kq = threadIdx.x & 31;
    int rr = threadIdx.x >> 5;
#pragma unroll
    for (int it = 0; it < 16; ++it) {
        int r = rr + it * 8;
        int gr = row0 + r;
        __half2 v = __floats2half2_rn(0.f, 0.f);
        if (gr < N) v = ((const __half2*)(h1 + (size_t)gr * 64))[kq];
        float2 fv = __half22float2(v);
        hT[(2 * kq + 0) * 129 + r] = fv.x;
        hT[(2 * kq + 1) * 129 + r] = fv.y;
    }
    __syncthreads();
    int tx = threadIdx.x & 7;
    int ty = threadIdx.x >> 3;
    float acc[4][4] = {};
#pragma unroll 4
    for (int k = 0; k < 64; ++k) {
        float4 a = *(const float4*)&hT[k * 129 + ty * 4];
        float4 b = *(const float4*)&Wl[k * 32 + tx * 4];
        acc[0][0] = fmaf(a.x, b.x, acc[0][0]);
        acc[0][1] = fmaf(a.x, b.y, acc[0][1]);
        acc[0][2] = fmaf(a.x, b.z, acc[0][2]);
        acc[0][3] = fmaf(a.x, b.w, acc[0][3]);
        acc[1][0] = fmaf(a.y, b.x, acc[1][0]);
        acc[1][1] = fmaf(a.y, b.y, acc[1][1]);
        acc[1][2] = fmaf(a.y, b.z, acc[1][2]);
        acc[1][3] = fmaf(a.y, b.w, acc[1][3]);
        acc[2][0] = fmaf(a.z, b.x, acc[2][0]);
        acc[2][1] = fmaf(a.z, b.y, acc[2][1]);
        acc[2][2] = fmaf(a.z, b.z, acc[2][2]);
        acc[2][3] = fmaf(a.z, b.w, acc[2][3]);
        acc[3][0] = fmaf(a.w, b.x, acc[3][0]);
        acc[3][1] = fmaf(a.w, b.y, acc[3][1]);
        acc[3][2] = fmaf(a.w, b.z, acc[3][2]);
        acc[3][3] = fmaf(a.w, b.w, acc[3][3]);
    }
    __half* dst = (tx < 4) ? g2a : g2b;
    int cq = (tx & 3) * 4;
#pragma unroll
    for (int i = 0; i < 4; ++i) {
        int gr = row0 + ty * 4 + i;
        if (gr < N) {
            float dr = dinv[gr];
            Half4 o;
            o.a = __floats2half2_rn(acc[i][0] * dr, acc[i][1] * dr);
            o.b = __floats2half2_rn(acc[i][2] * dr, acc[i][3] * dr);
            *(Half4*)(dst + (size_t)gr * 16 + cq) = o;
        }
    }
}

// feature-sliced agg layer2: 8 lanes/node, gs = one 3.2 MB slice (N x 8 half2),
// outs pre-offset into out (row stride 16 float2); b2s pre-offset bias.
__global__ __launch_bounds__(THREADS) void k_agg2s(const int* __restrict__ rowptr,
                                                   const int* __restrict__ csr,
                                                   const __half2* __restrict__ gs,
                                                   const float* __restrict__ dinv,
                                                   const float* __restrict__ b2s,
                                                   float2* __restrict__ outs, int N) {
    int v = (blockIdx.x * THREADS + threadIdx.x) >> 3;
    if (v >= N) return;
    int f = threadIdx.x & 7;
    int beg = rowptr[v], end = rowptr[v + 1];
    float2 s = __half22float2(gs[(size_t)v * 8 + f]);
    float sx = s.x, sy = s.y;
    int j = beg;
    for (; j + 16 <= end; j += 16) {
        int idx[16];
#pragma unroll
        for (int u = 0; u < 16; ++u) idx[u] = csr[j + u];
        __half2 a[16];
#pragma unroll
        for (int u = 0; u < 16; ++u) a[u] = gs[(size_t)idx[u] * 8 + f];
        float tx = 0.f, ty = 0.f;
#pragma unroll
        for (int u = 0; u < 16; ++u) {
            float2 fa = __half22float2(a[u]);
            tx += fa.x; ty += fa.y;
        }
        sx += tx; sy += ty;
    }
    if (j + 8 <= end) {
        int idx[8];
#pragma unroll
        for (int u = 0; u < 8; ++u) idx[u] = csr[j + u];
        __half2 a[8];
#pragma unroll
        for (int u = 0; u < 8; ++u) a[u] = gs[(size_t)idx[u] * 8 + f];
#pragma unroll
        for (int u = 0; u < 8; ++u) {
            float2 fa = __half22float2(a[u]);
            sx += fa.x; sy += fa.y;
        }
        j += 8;
    }
    for (; j < end; ++j) {
        float2 a = __half22float2(gs[(size_t)csr[j] * 8 + f]);
        sx += a.x; sy += a.y;
    }
    float dr = dinv[v];
    float2 o;
    o.x = fmaf(dr, sx, b2s[2 * f + 0]);
    o.y = fmaf(dr, sy, b2s[2 * f + 1]);
    outs[(size_t)v * 16 + f] = o;
}

extern "C" void kernel_launch(void* const* d_in, const int* in_sizes, int n_in,
                              void* d_out, int out_size, void* d_ws, size_t ws_size,
                              hipStream_t stream) {
    const float* x  = (const float*)d_in[0];
    const int* eidx = (const int*)d_in[1];
    const float* W1 = (const float*)d_in[2];
    const float* b1 = (const float*)d_in[3];
    const float* W2 = (const float*)d_in[4];
    const float* b2 = (const float*)d_in[5];
    float* out = (float*)d_out;

    const int N = in_sizes[0] / 128;   // 100000
    const int E = in_sizes[1] / 2;     // 3200000
    const int K = (N + NB - 1) / NB;   // 391
    const int C = (E + NCHUNK - 1) / NCHUNK;

    // ws layout (ints), no aliasing; total ~61 MB
    int* flag   = (int*)d_ws;                            // 64
    int* H      = flag + 64;                             // NCHUNK*400
    int* btot   = H + (size_t)NCHUNK * 400;              // 400
    int* base   = btot + 400;                            // 448
    unsigned int* packed = (unsigned int*)(base + 448);  // E
    int* csr    = (int*)(packed + E);                    // E
    int* rowptr = csr + E;                               // N+1 (100032)
    float* dinv = (float*)(rowptr + 100032);             // 100032
    __half* g1a = (__half*)(dinv + 100032);              // N*32 halfs
    __half* g1b = g1a + (size_t)N * 32;                  // N*32 halfs
    __half* h1  = g1b + (size_t)N * 32;                  // N*64 halfs (unified)
    __half* g2a = h1 + (size_t)N * 64;                   // N*16 halfs
    __half* g2b = g2a + (size_t)N * 16;                  // N*16 halfs

    k_detect<<<1, 64, 0, stream>>>(eidx, flag);
    k_hist<<<NCHUNK, HTHREADS, 0, stream>>>(eidx, flag, E, C, K, H);
    k_colscan<<<(K * 64 + THREADS - 1) / THREADS, THREADS, 0, stream>>>(H, btot, K, NCHUNK);
    k_basescan<<<1, 1024, 0, stream>>>(btot, base, K);
    k_passB<<<NCHUNK, HTHREADS, 0, stream>>>(eidx, flag, E, C, K, H, base, packed);
    k_passC<<<K, NB, 0, stream>>>(packed, base, K, N, csr, rowptr, dinv);
    k_gemm1<<<(N + 63) / 64, THREADS, 0, stream>>>(x, W1, dinv, g1a, g1b, N);
    int gA1 = (N * 16 + THREADS - 1) / THREADS;
    k_agg1s<<<gA1, THREADS, 0, stream>>>(rowptr, csr, (const __half2*)g1a, dinv,
                                         b1, (__half2*)h1, N);
    k_agg1s<<<gA1, THREADS, 0, stream>>>(rowptr, csr, (const __half2*)g1b, dinv,
                                         b1 + 32, (__half2*)h1 + 16, N);
    k_gemm2<<<(N + 127) / 128, THREADS, 0, stream>>>(h1, W2, dinv, g2a, g2b, N);
    int gA2 = (N * 8 + THREADS - 1) / THREADS;
    k_agg2s<<<gA2, THREADS, 0, stream>>>(rowptr, csr, (const __half2*)g2a, dinv,
                                         b2, (float2*)out, N);
    k_agg2s<<<gA2, THREADS, 0, stream>>>(rowptr, csr, (const __half2*)g2b, dinv,
                                         b2 + 16, (float2*)out + 8, N);
}

// Round 12
// 267.836 us; speedup vs baseline: 1.0489x; 1.0489x over previous
//
#include <hip/hip_runtime.h>
#include <hip/hip_fp16.h>

#define THREADS 256
#define HTHREADS 1024
#define NB 256           // nodes per bucket
#define KMAX 400         // >= ceil(N/NB)=391
#define NCHUNK 512       // edge chunks (16 edges/bucket/chunk = 64B frontiers)

struct alignas(8) Half4 { __half2 a, b; };

// ---------------------------------------------------------------------------
// detect -> hist -> colscan (wave/bucket) -> basescan -> passB -> passC ->
// gemm1 (reg-blocked, W1 from L1, writes SPLIT g1a/g1b) ->
// agg1s x2 (feature-sliced gather) -> gemm2 (writes SPLIT g2a/g2b) ->
// agg2s x2 (out slices)
//
// R11 lessons: (1) gemm1 at 2 blocks/CU (66KB LDS) = 16% occupancy; W1 is
// L1-sized, stage only xT in LDS. (2) passB 5x write amplification at
// NCHUNK=1024 (32B frontiers); NCHUNK=512 doubles frontier regions to 64B.
// packed edge = (src << 8) | (dst & 255); bucket = dst >> 8
// ---------------------------------------------------------------------------

__global__ void k_detect(const int* __restrict__ e32, int* __restrict__ flag) {
    if (blockIdx.x == 0 && threadIdx.x == 0) {
        int st = 2;
        for (int i = 0; i < 64; ++i)
            if (e32[2 * i + 1] != 0) { st = 1; break; }
        *flag = st;
    }
}

__global__ __launch_bounds__(HTHREADS) void k_hist(const int* __restrict__ eidx,
                                                   const int* __restrict__ flag,
                                                   int E, int C, int K,
                                                   int* __restrict__ H) {
    __shared__ int hl[KMAX];
    int st = *flag;
    for (int i = threadIdx.x; i < K; i += HTHREADS) hl[i] = 0;
    __syncthreads();
    int s0 = blockIdx.x * C;
    int s1 = min(s0 + C, E);
    for (int e = s0 + threadIdx.x; e < s1; e += HTHREADS) {
        int d = eidx[(size_t)(E + e) * st];
        atomicAdd(&hl[d >> 8], 1);
    }
    __syncthreads();
    for (int i = threadIdx.x; i < K; i += HTHREADS)
        H[(size_t)blockIdx.x * K + i] = hl[i];
}

// wave per bucket: exclusive prefix of H[c][b] over c, 64 chunks/iteration
__global__ __launch_bounds__(THREADS) void k_colscan(int* __restrict__ H,
                                                     int* __restrict__ btot,
                                                     int K, int nchunk) {
    int b = (blockIdx.x * THREADS + threadIdx.x) >> 6;
    if (b >= K) return;
    int lane = threadIdx.x & 63;
    int run = 0;
    for (int i = 0; i < nchunk; i += 64) {
        int c = i + lane;
        int v = H[(size_t)c * K + b];
        int xs = v;
#pragma unroll
        for (int off = 1; off < 64; off <<= 1) {
            int t = __shfl_up(xs, off, 64);
            if (lane >= off) xs += t;
        }
        H[(size_t)c * K + b] = run + (xs - v);
        run += __shfl(xs, 63, 64);
    }
    if (lane == 0) btot[b] = run;
}

// exclusive scan of K<=2048 bucket totals, single block
__global__ __launch_bounds__(1024) void k_basescan(const int* __restrict__ btot,
                                                   int* __restrict__ base, int K) {
    __shared__ int s0[2048], s1[2048];
    int t = threadIdx.x;
    for (int i = t; i < 2048; i += 1024) s0[i] = (i < K) ? btot[i] : 0;
    __syncthreads();
    int* src = s0; int* dst = s1;
    for (int off = 1; off < 2048; off <<= 1) {
        for (int i = t; i < 2048; i += 1024)
            dst[i] = src[i] + (i >= off ? src[i - off] : 0);
        __syncthreads();
        int* tmp = src; src = dst; dst = tmp;
    }
    for (int i = t; i < 2048; i += 1024)
        if (i < K) base[i] = (i == 0) ? 0 : src[i - 1];
    if (t == 0) base[K] = src[K - 1];
}

__global__ __launch_bounds__(HTHREADS) void k_passB(const int* __restrict__ eidx,
                                                    const int* __restrict__ flag,
                                                    int E, int C, int K,
                                                    const int* __restrict__ H,
                                                    const int* __restrict__ base,
                                                    unsigned int* __restrict__ packed) {
    __shared__ int cur[KMAX];
    int st = *flag;
    for (int i = threadIdx.x; i < K; i += HTHREADS)
        cur[i] = base[i] + H[(size_t)blockIdx.x * K + i];
    __syncthreads();
    int s0 = blockIdx.x * C;
    int s1 = min(s0 + C, E);
    for (int e = s0 + threadIdx.x; e < s1; e += HTHREADS) {
        int s = eidx[(size_t)e * st];
        int d = eidx[(size_t)(E + e) * st];
        int pos = atomicAdd(&cur[d >> 8], 1);
        packed[pos] = ((unsigned)s << 8) | (unsigned)(d & 255);
    }
}

// per-bucket counting sort: packed -> csr (src by node), rowptr, dinv
__global__ __launch_bounds__(NB) void k_passC(const unsigned int* __restrict__ pk,
                                              const int* __restrict__ base,
                                              int K, int N,
                                              int* __restrict__ csr,
                                              int* __restrict__ rowptr,
                                              float* __restrict__ dinv) {
    __shared__ int cnt[NB];
    __shared__ int scn[NB];
    __shared__ int cur[NB];
    int b = blockIdx.x;
    int b0 = base[b], b1e = base[b + 1];
    int t = threadIdx.x;
    cnt[t] = 0;
    __syncthreads();
    for (int e = b0 + t; e < b1e; e += NB)
        atomicAdd(&cnt[pk[e] & 255u], 1);
    __syncthreads();
    int val = cnt[t];
    scn[t] = val;
    __syncthreads();
    for (int off = 1; off < NB; off <<= 1) {
        int tmp = (t >= off) ? scn[t - off] : 0;
        __syncthreads();
        scn[t] += tmp;
        __syncthreads();
    }
    int excl = b0 + scn[t] - val;
    cur[t] = excl;
    int v = b * NB + t;
    if (v < N) {
        rowptr[v] = excl;
        dinv[v] = rsqrtf((float)val + 1.0f);
    }
    if (b == K - 1 && t == 0) rowptr[N] = b1e;
    __syncthreads();
    for (int e = b0 + t; e < b1e; e += NB) {
        unsigned p = pk[e];
        int pos = atomicAdd(&cur[p & 255u], 1);
        csr[pos] = (int)(p >> 8);
    }
}

// reg-blocked GEMM1: 64-row tile, 4x4 per thread; xT in LDS, W1 from L1.
__global__ __launch_bounds__(THREADS) void k_gemm1(const float* __restrict__ x,
                                                   const float* __restrict__ W1,
                                                   const float* __restrict__ dinv,
                                                   __half* __restrict__ g1a,
                                                   __half* __restrict__ g1b, int N) {
    __shared__ float xT[128 * 65];
    int row0 = blockIdx.x * 64;
    int kq = threadIdx.x & 31;
    int rr = threadIdx.x >> 5;
#pragma unroll
    for (int it = 0; it < 8; ++it) {
        int r = rr + it * 8;
        int gr = row0 + r;
        float4 xv = make_float4(0.f, 0.f, 0.f, 0.f);
        if (gr < N) xv = *(const float4*)(x + (size_t)gr * 128 + kq * 4);
        xT[(4 * kq + 0) * 65 + r] = xv.x;
        xT[(4 * kq + 1) * 65 + r] = xv.y;
        xT[(4 * kq + 2) * 65 + r] = xv.z;
        xT[(4 * kq + 3) * 65 + r] = xv.w;
    }
    __syncthreads();
    int tx = threadIdx.x & 15;
    int ty = threadIdx.x >> 4;
    float acc[4][4] = {};
#pragma unroll 4
    for (int k = 0; k < 128; ++k) {
        float4 a = *(const float4*)&xT[k * 65 + ty * 4];
        float4 b = *(const float4*)(W1 + k * 64 + tx * 4);  // L1-resident
        acc[0][0] = fmaf(a.x, b.x, acc[0][0]);
        acc[0][1] = fmaf(a.x, b.y, acc[0][1]);
        acc[0][2] = fmaf(a.x, b.z, acc[0][2]);
        acc[0][3] = fmaf(a.x, b.w, acc[0][3]);
        acc[1][0] = fmaf(a.y, b.x, acc[1][0]);
        acc[1][1] = fmaf(a.y, b.y, acc[1][1]);
        acc[1][2] = fmaf(a.y, b.z, acc[1][2]);
        acc[1][3] = fmaf(a.y, b.w, acc[1][3]);
        acc[2][0] = fmaf(a.z, b.x, acc[2][0]);
        acc[2][1] = fmaf(a.z, b.y, acc[2][1]);
        acc[2][2] = fmaf(a.z, b.z, acc[2][2]);
        acc[2][3] = fmaf(a.z, b.w, acc[2][3]);
        acc[3][0] = fmaf(a.w, b.x, acc[3][0]);
        acc[3][1] = fmaf(a.w, b.y, acc[3][1]);
        acc[3][2] = fmaf(a.w, b.z, acc[3][2]);
        acc[3][3] = fmaf(a.w, b.w, acc[3][3]);
    }
    __half* dst = (tx < 8) ? g1a : g1b;
    int cq = (tx & 7) * 4;
#pragma unroll
    for (int i = 0; i < 4; ++i) {
        int gr = row0 + ty * 4 + i;
        if (gr < N) {
            float dr = dinv[gr];
            Half4 o;
            o.a = __floats2half2_rn(acc[i][0] * dr, acc[i][1] * dr);
            o.b = __floats2half2_rn(acc[i][2] * dr, acc[i][3] * dr);
            *(Half4*)(dst + (size_t)gr * 32 + cq) = o;
        }
    }
}

// feature-sliced agg layer1: 16 lanes/node, gs = one 6.4 MB slice
__global__ __launch_bounds__(THREADS) void k_agg1s(const int* __restrict__ rowptr,
                                                   const int* __restrict__ csr,
                                                   const __half2* __restrict__ gs,
                                                   const float* __restrict__ dinv,
                                                   const float* __restrict__ b1s,
                                                   __half2* __restrict__ h1s, int N) {
    int v = (blockIdx.x * THREADS + threadIdx.x) >> 4;
    if (v >= N) return;
    int f = threadIdx.x & 15;
    int beg = rowptr[v], end = rowptr[v + 1];
    float2 s = __half22float2(gs[(size_t)v * 16 + f]);
    float sx = s.x, sy = s.y;
    int j = beg;
    for (; j + 16 <= end; j += 16) {
        int idx[16];
#pragma unroll
        for (int u = 0; u < 16; ++u) idx[u] = csr[j + u];
        __half2 a[16];
#pragma unroll
        for (int u = 0; u < 16; ++u) a[u] = gs[(size_t)idx[u] * 16 + f];
        float tx = 0.f, ty = 0.f;
#pragma unroll
        for (int u = 0; u < 16; ++u) {
            float2 fa = __half22float2(a[u]);
            tx += fa.x; ty += fa.y;
        }
        sx += tx; sy += ty;
    }
    if (j + 8 <= end) {
        int idx[8];
#pragma unroll
        for (int u = 0; u < 8; ++u) idx[u] = csr[j + u];
        __half2 a[8];
#pragma unroll
        for (int u = 0; u < 8; ++u) a[u] = gs[(size_t)idx[u] * 16 + f];
#pragma unroll
        for (int u = 0; u < 8; ++u) {
            float2 fa = __half22float2(a[u]);
            sx += fa.x; sy += fa.y;
        }
        j += 8;
    }
    for (; j < end; ++j) {
        float2 a = __half22float2(gs[(size_t)csr[j] * 16 + f]);
        sx += a.x; sy += a.y;
    }
    float dr = dinv[v];
    float h0 = fmaxf(fmaf(dr, sx, b1s[2 * f + 0]), 0.0f);
    float h1v = fmaxf(fmaf(dr, sy, b1s[2 * f + 1]), 0.0f);
    h1s[(size_t)v * 32 + f] = __floats2half2_rn(h0, h1v);
}

// reg-blocked GEMM2: reads unified h1; writes split g2a/g2b
__global__ __launch_bounds__(THREADS) void k_gemm2(const __half* __restrict__ h1,
                                                   const float* __restrict__ W2,
                                                   const float* __restrict__ dinv,
                                                   __half* __restrict__ g2a,
                                                   __half* __restrict__ g2b, int N) {
    __shared__ float hT[64 * 129];
    __shared__ float Wl[64 * 32];
    for (int i = threadIdx.x; i < 64 * 32; i += THREADS) Wl[i] = W2[i];
    int row0 = blockIdx.x * 128;
    int kq = threadIdx.x & 31;
    int rr = threadIdx.x >> 5;
#pragma unroll
    for (int it = 0; it < 16; ++it) {
        int r = rr + it * 8;
        int gr = row0 + r;
        __half2 v = __floats2half2_rn(0.f, 0.f);
        if (gr < N) v = ((const __half2*)(h1 + (size_t)gr * 64))[kq];
        float2 fv = __half22float2(v);
        hT[(2 * kq + 0) * 129 + r] = fv.x;
        hT[(2 * kq + 1) * 129 + r] = fv.y;
    }
    __syncthreads();
    int tx = threadIdx.x & 7;
    int ty = threadIdx.x >> 3;
    float acc[4][4] = {};
#pragma unroll 4
    for (int k = 0; k < 64; ++k) {
        float4 a = *(const float4*)&hT[k * 129 + ty * 4];
        float4 b = *(const float4*)&Wl[k * 32 + tx * 4];
        acc[0][0] = fmaf(a.x, b.x, acc[0][0]);
        acc[0][1] = fmaf(a.x, b.y, acc[0][1]);
        acc[0][2] = fmaf(a.x, b.z, acc[0][2]);
        acc[0][3] = fmaf(a.x, b.w, acc[0][3]);
        acc[1][0] = fmaf(a.y, b.x, acc[1][0]);
        acc[1][1] = fmaf(a.y, b.y, acc[1][1]);
        acc[1][2] = fmaf(a.y, b.z, acc[1][2]);
        acc[1][3] = fmaf(a.y, b.w, acc[1][3]);
        acc[2][0] = fmaf(a.z, b.x, acc[2][0]);
        acc[2][1] = fmaf(a.z, b.y, acc[2][1]);
        acc[2][2] = fmaf(a.z, b.z, acc[2][2]);
        acc[2][3] = fmaf(a.z, b.w, acc[2][3]);
        acc[3][0] = fmaf(a.w, b.x, acc[3][0]);
        acc[3][1] = fmaf(a.w, b.y, acc[3][1]);
        acc[3][2] = fmaf(a.w, b.z, acc[3][2]);
        acc[3][3] = fmaf(a.w, b.w, acc[3][3]);
    }
    __half* dst = (tx < 4) ? g2a : g2b;
    int cq = (tx & 3) * 4;
#pragma unroll
    for (int i = 0; i < 4; ++i) {
        int gr = row0 + ty * 4 + i;
        if (gr < N) {
            float dr = dinv[gr];
            Half4 o;
            o.a = __floats2half2_rn(acc[i][0] * dr, acc[i][1] * dr);
            o.b = __floats2half2_rn(acc[i][2] * dr, acc[i][3] * dr);
            *(Half4*)(dst + (size_t)gr * 16 + cq) = o;
        }
    }
}

// feature-sliced agg layer2: 8 lanes/node, gs = one 3.2 MB slice
__global__ __launch_bounds__(THREADS) void k_agg2s(const int* __restrict__ rowptr,
                                                   const int* __restrict__ csr,
                                                   const __half2* __restrict__ gs,
                                                   const float* __restrict__ dinv,
                                                   const float* __restrict__ b2s,
                                                   float2* __restrict__ outs, int N) {
    int v = (blockIdx.x * THREADS + threadIdx.x) >> 3;
    if (v >= N) return;
    int f = threadIdx.x & 7;
    int beg = rowptr[v], end = rowptr[v + 1];
    float2 s = __half22float2(gs[(size_t)v * 8 + f]);
    float sx = s.x, sy = s.y;
    int j = beg;
    for (; j + 16 <= end; j += 16) {
        int idx[16];
#pragma unroll
        for (int u = 0; u < 16; ++u) idx[u] = csr[j + u];
        __half2 a[16];
#pragma unroll
        for (int u = 0; u < 16; ++u) a[u] = gs[(size_t)idx[u] * 8 + f];
        float tx = 0.f, ty = 0.f;
#pragma unroll
        for (int u = 0; u < 16; ++u) {
            float2 fa = __half22float2(a[u]);
            tx += fa.x; ty += fa.y;
        }
        sx += tx; sy += ty;
    }
    if (j + 8 <= end) {
        int idx[8];
#pragma unroll
        for (int u = 0; u < 8; ++u) idx[u] = csr[j + u];
        __half2 a[8];
#pragma unroll
        for (int u = 0; u < 8; ++u) a[u] = gs[(size_t)idx[u] * 8 + f];
#pragma unroll
        for (int u = 0; u < 8; ++u) {
            float2 fa = __half22float2(a[u]);
            sx += fa.x; sy += fa.y;
        }
        j += 8;
    }
    for (; j < end; ++j) {
        float2 a = __half22float2(gs[(size_t)csr[j] * 8 + f]);
        sx += a.x; sy += a.y;
    }
    float dr = dinv[v];
    float2 o;
    o.x = fmaf(dr, sx, b2s[2 * f + 0]);
    o.y = fmaf(dr, sy, b2s[2 * f + 1]);
    outs[(size_t)v * 16 + f] = o;
}

extern "C" void kernel_launch(void* const* d_in, const int* in_sizes, int n_in,
                              void* d_out, int out_size, void* d_ws, size_t ws_size,
                              hipStream_t stream) {
    const float* x  = (const float*)d_in[0];
    const int* eidx = (const int*)d_in[1];
    const float* W1 = (const float*)d_in[2];
    const float* b1 = (const float*)d_in[3];
    const float* W2 = (const float*)d_in[4];
    const float* b2 = (const float*)d_in[5];
    float* out = (float*)d_out;

    const int N = in_sizes[0] / 128;   // 100000
    const int E = in_sizes[1] / 2;     // 3200000
    const int K = (N + NB - 1) / NB;   // 391
    const int C = (E + NCHUNK - 1) / NCHUNK;

    // ws layout (ints), no aliasing
    int* flag   = (int*)d_ws;                            // 64
    int* H      = flag + 64;                             // NCHUNK*400
    int* btot   = H + (size_t)NCHUNK * 400;              // 400
    int* base   = btot + 400;                            // 448
    unsigned int* packed = (unsigned int*)(base + 448);  // E
    int* csr    = (int*)(packed + E);                    // E
    int* rowptr = csr + E;                               // N+1 (100032)
    float* dinv = (float*)(rowptr + 100032);             // 100032
    __half* g1a = (__half*)(dinv + 100032);              // N*32 halfs
    __half* g1b = g1a + (size_t)N * 32;                  // N*32 halfs
    __half* h1  = g1b + (size_t)N * 32;                  // N*64 halfs (unified)
    __half* g2a = h1 + (size_t)N * 64;                   // N*16 halfs
    __half* g2b = g2a + (size_t)N * 16;                  // N*16 halfs

    k_detect<<<1, 64, 0, stream>>>(eidx, flag);
    k_hist<<<NCHUNK, HTHREADS, 0, stream>>>(eidx, flag, E, C, K, H);
    k_colscan<<<(K * 64 + THREADS - 1) / THREADS, THREADS, 0, stream>>>(H, btot, K, NCHUNK);
    k_basescan<<<1, 1024, 0, stream>>>(btot, base, K);
    k_passB<<<NCHUNK, HTHREADS, 0, stream>>>(eidx, flag, E, C, K, H, base, packed);
    k_passC<<<K, NB, 0, stream>>>(packed, base, K, N, csr, rowptr, dinv);
    k_gemm1<<<(N + 63) / 64, THREADS, 0, stream>>>(x, W1, dinv, g1a, g1b, N);
    int gA1 = (N * 16 + THREADS - 1) / THREADS;
    k_agg1s<<<gA1, THREADS, 0, stream>>>(rowptr, csr, (const __half2*)g1a, dinv,
                                         b1, (__half2*)h1, N);
    k_agg1s<<<gA1, THREADS, 0, stream>>>(rowptr, csr, (const __half2*)g1b, dinv,
                                         b1 + 32, (__half2*)h1 + 16, N);
    k_gemm2<<<(N + 127) / 128, THREADS, 0, stream>>>(h1, W2, dinv, g2a, g2b, N);
    int gA2 = (N * 8 + THREADS - 1) / THREADS;
    k_agg2s<<<gA2, THREADS, 0, stream>>>(rowptr, csr, (const __half2*)g2a, dinv,
                                         b2, (float2*)out, N);
    k_agg2s<<<gA2, THREADS, 0, stream>>>(rowptr, csr, (const __half2*)g2b, dinv,
                                         b2 + 16, (float2*)out + 8, N);
}

// Round 13
// 239.352 us; speedup vs baseline: 1.1737x; 1.1190x over previous
//
#include <hip/hip_runtime.h>
#include <hip/hip_fp16.h>

#define THREADS 256
#define HTHREADS 1024
#define NB 256           // nodes per bucket
#define KMAX 400         // >= ceil(N/NB)=391
#define NCHUNK 512       // edge chunks for bucket sort

struct alignas(8) Half4 { __half2 a, b; };
typedef _Float16 half8 __attribute__((ext_vector_type(8)));
typedef float floatx4 __attribute__((ext_vector_type(4)));

// ---------------------------------------------------------------------------
// detect -> hist -> colscan -> basescan -> passB -> passC ->
// gemm1 (MFMA 16x16x32 f16, no LDS, wave=16x64 tile) ->
// agg1 (unified 128B-row gather, 16-deep) -> gemm2 (reg-blocked 4x4) ->
// agg2 (unified, 16-deep)
//
// R12 lessons: (1) VALU gemm1 structurally stuck at ~50 us (L1-load->FMA
// chains); MFMA kills the compute wall. (2) 64B gather rows waste half a
// 128B line per miss -> unified 128B rows are optimal; feature-split reverted.
// MFMA layouts (m89-verified C/D): D row=(lane>>4)*4+reg, col=lane&15;
// A row=lane&15 k=(lane>>4)*8+j; B col=lane&15 k=(lane>>4)*8+j.
// packed edge = (src << 8) | (dst & 255); bucket = dst >> 8
// ---------------------------------------------------------------------------

__global__ void k_detect(const int* __restrict__ e32, int* __restrict__ flag) {
    if (blockIdx.x == 0 && threadIdx.x == 0) {
        int st = 2;
        for (int i = 0; i < 64; ++i)
            if (e32[2 * i + 1] != 0) { st = 1; break; }
        *flag = st;
    }
}

__global__ __launch_bounds__(HTHREADS) void k_hist(const int* __restrict__ eidx,
                                                   const int* __restrict__ flag,
                                                   int E, int C, int K,
                                                   int* __restrict__ H) {
    __shared__ int hl[KMAX];
    int st = *flag;
    for (int i = threadIdx.x; i < K; i += HTHREADS) hl[i] = 0;
    __syncthreads();
    int s0 = blockIdx.x * C;
    int s1 = min(s0 + C, E);
    for (int e = s0 + threadIdx.x; e < s1; e += HTHREADS) {
        int d = eidx[(size_t)(E + e) * st];
        atomicAdd(&hl[d >> 8], 1);
    }
    __syncthreads();
    for (int i = threadIdx.x; i < K; i += HTHREADS)
        H[(size_t)blockIdx.x * K + i] = hl[i];
}

// wave per bucket: exclusive prefix of H[c][b] over c
__global__ __launch_bounds__(THREADS) void k_colscan(int* __restrict__ H,
                                                     int* __restrict__ btot,
                                                     int K, int nchunk) {
    int b = (blockIdx.x * THREADS + threadIdx.x) >> 6;
    if (b >= K) return;
    int lane = threadIdx.x & 63;
    int run = 0;
    for (int i = 0; i < nchunk; i += 64) {
        int c = i + lane;
        int v = H[(size_t)c * K + b];
        int xs = v;
#pragma unroll
        for (int off = 1; off < 64; off <<= 1) {
            int t = __shfl_up(xs, off, 64);
            if (lane >= off) xs += t;
        }
        H[(size_t)c * K + b] = run + (xs - v);
        run += __shfl(xs, 63, 64);
    }
    if (lane == 0) btot[b] = run;
}

// exclusive scan of K<=2048 bucket totals, single block
__global__ __launch_bounds__(1024) void k_basescan(const int* __restrict__ btot,
                                                   int* __restrict__ base, int K) {
    __shared__ int s0[2048], s1[2048];
    int t = threadIdx.x;
    for (int i = t; i < 2048; i += 1024) s0[i] = (i < K) ? btot[i] : 0;
    __syncthreads();
    int* src = s0; int* dst = s1;
    for (int off = 1; off < 2048; off <<= 1) {
        for (int i = t; i < 2048; i += 1024)
            dst[i] = src[i] + (i >= off ? src[i - off] : 0);
        __syncthreads();
        int* tmp = src; src = dst; dst = tmp;
    }
    for (int i = t; i < 2048; i += 1024)
        if (i < K) base[i] = (i == 0) ? 0 : src[i - 1];
    if (t == 0) base[K] = src[K - 1];
}

__global__ __launch_bounds__(HTHREADS) void k_passB(const int* __restrict__ eidx,
                                                    const int* __restrict__ flag,
                                                    int E, int C, int K,
                                                    const int* __restrict__ H,
                                                    const int* __restrict__ base,
                                                    unsigned int* __restrict__ packed) {
    __shared__ int cur[KMAX];
    int st = *flag;
    for (int i = threadIdx.x; i < K; i += HTHREADS)
        cur[i] = base[i] + H[(size_t)blockIdx.x * K + i];
    __syncthreads();
    int s0 = blockIdx.x * C;
    int s1 = min(s0 + C, E);
    for (int e = s0 + threadIdx.x; e < s1; e += HTHREADS) {
        int s = eidx[(size_t)e * st];
        int d = eidx[(size_t)(E + e) * st];
        int pos = atomicAdd(&cur[d >> 8], 1);
        packed[pos] = ((unsigned)s << 8) | (unsigned)(d & 255);
    }
}

// per-bucket counting sort: packed -> csr (src by node), rowptr, dinv
__global__ __launch_bounds__(NB) void k_passC(const unsigned int* __restrict__ pk,
                                              const int* __restrict__ base,
                                              int K, int N,
                                              int* __restrict__ csr,
                                              int* __restrict__ rowptr,
                                              float* __restrict__ dinv) {
    __shared__ int cnt[NB];
    __shared__ int scn[NB];
    __shared__ int cur[NB];
    int b = blockIdx.x;
    int b0 = base[b], b1e = base[b + 1];
    int t = threadIdx.x;
    cnt[t] = 0;
    __syncthreads();
    for (int e = b0 + t; e < b1e; e += NB)
        atomicAdd(&cnt[pk[e] & 255u], 1);
    __syncthreads();
    int val = cnt[t];
    scn[t] = val;
    __syncthreads();
    for (int off = 1; off < NB; off <<= 1) {
        int tmp = (t >= off) ? scn[t - off] : 0;
        __syncthreads();
        scn[t] += tmp;
        __syncthreads();
    }
    int excl = b0 + scn[t] - val;
    cur[t] = excl;
    int v = b * NB + t;
    if (v < N) {
        rowptr[v] = excl;
        dinv[v] = rsqrtf((float)val + 1.0f);
    }
    if (b == K - 1 && t == 0) rowptr[N] = b1e;
    __syncthreads();
    for (int e = b0 + t; e < b1e; e += NB) {
        unsigned p = pk[e];
        int pos = atomicAdd(&cur[p & 255u], 1);
        csr[pos] = (int)(p >> 8);
    }
}

// MFMA GEMM1: wave computes 16 rows x 64 cols; block = 4 waves = 64 rows.
// g1[r][c] = half((x[r,:] @ W1[:,c]) * dinv[r]); fp16 inputs, fp32 accum.
__global__ __launch_bounds__(THREADS) void k_gemm1(const float* __restrict__ x,
                                                   const float* __restrict__ W1,
                                                   const float* __restrict__ dinv,
                                                   __half* __restrict__ g1, int N) {
    int wid = threadIdx.x >> 6;
    int lane = threadIdx.x & 63;
    int r0 = blockIdx.x * 64 + wid * 16;
    int lrow = lane & 15;
    int khi = lane >> 4;              // 0..3
    int arow = min(r0 + lrow, N - 1);

    // A fragments: 4 k-tiles, lane holds x[arow][kt*32 + khi*8 .. +7]
    half8 a[4];
    const float* xr = x + (size_t)arow * 128 + khi * 8;
#pragma unroll
    for (int kt = 0; kt < 4; ++kt) {
        float4 v0 = *(const float4*)(xr + kt * 32);
        float4 v1 = *(const float4*)(xr + kt * 32 + 4);
        half8 h;
        h[0] = (_Float16)v0.x; h[1] = (_Float16)v0.y;
        h[2] = (_Float16)v0.z; h[3] = (_Float16)v0.w;
        h[4] = (_Float16)v1.x; h[5] = (_Float16)v1.y;
        h[6] = (_Float16)v1.z; h[7] = (_Float16)v1.w;
        a[kt] = h;
    }

    floatx4 acc[4] = {};
#pragma unroll
    for (int ct = 0; ct < 4; ++ct) {
#pragma unroll
        for (int kt = 0; kt < 4; ++kt) {
            // B frag: W1[kt*32 + khi*8 + j][ct*16 + lrow], stride 64 floats
            const float* wp = W1 + (size_t)(kt * 32 + khi * 8) * 64 + ct * 16 + lrow;
            half8 b;
#pragma unroll
            for (int j = 0; j < 8; ++j) b[j] = (_Float16)wp[(size_t)j * 64];
            acc[ct] = __builtin_amdgcn_mfma_f32_16x16x32_f16(a[kt], b, acc[ct], 0, 0, 0);
        }
    }

    // D: row = (lane>>4)*4 + reg, col = lane&15 (within 16x16 tile)
#pragma unroll
    for (int reg = 0; reg < 4; ++reg) {
        int r = r0 + khi * 4 + reg;
        if (r < N) {
            float dr = dinv[r];
#pragma unroll
            for (int ct = 0; ct < 4; ++ct)
                g1[(size_t)r * 64 + ct * 16 + lrow] = __float2half(acc[ct][reg] * dr);
        }
    }
}

// 32 lanes per node, lane f = half2 feature pair; 16-deep gather pipeline
__global__ __launch_bounds__(THREADS) void k_agg1(const int* __restrict__ rowptr,
                                                  const int* __restrict__ csr,
                                                  const __half* __restrict__ g1h,
                                                  const float* __restrict__ dinv,
                                                  const float* __restrict__ b1,
                                                  __half* __restrict__ h1h, int N) {
    const __half2* g1 = (const __half2*)g1h;
    __half2* h1 = (__half2*)h1h;
    int v = (blockIdx.x * THREADS + threadIdx.x) >> 5;
    if (v >= N) return;
    int f = threadIdx.x & 31;
    int beg = rowptr[v], end = rowptr[v + 1];
    float2 s = __half22float2(g1[(size_t)v * 32 + f]);
    float sx = s.x, sy = s.y;
    int j = beg;
    for (; j + 16 <= end; j += 16) {
        int idx[16];
#pragma unroll
        for (int u = 0; u < 16; ++u) idx[u] = csr[j + u];
        __half2 a[16];
#pragma unroll
        for (int u = 0; u < 16; ++u) a[u] = g1[(size_t)idx[u] * 32 + f];
        float tx = 0.f, ty = 0.f;
#pragma unroll
        for (int u = 0; u < 16; ++u) {
            float2 fa = __half22float2(a[u]);
            tx += fa.x; ty += fa.y;
        }
        sx += tx; sy += ty;
    }
    if (j + 8 <= end) {
        int idx[8];
#pragma unroll
        for (int u = 0; u < 8; ++u) idx[u] = csr[j + u];
        __half2 a[8];
#pragma unroll
        for (int u = 0; u < 8; ++u) a[u] = g1[(size_t)idx[u] * 32 + f];
#pragma unroll
        for (int u = 0; u < 8; ++u) {
            float2 fa = __half22float2(a[u]);
            sx += fa.x; sy += fa.y;
        }
        j += 8;
    }
    for (; j < end; ++j) {
        float2 a = __half22float2(g1[(size_t)csr[j] * 32 + f]);
        sx += a.x; sy += a.y;
    }
    float dr = dinv[v];
    float h0 = fmaxf(fmaf(dr, sx, b1[2 * f + 0]), 0.0f);
    float h1v = fmaxf(fmaf(dr, sy, b1[2 * f + 1]), 0.0f);
    h1[(size_t)v * 32 + f] = __floats2half2_rn(h0, h1v);
}

// reg-blocked GEMM2: 128-row tile, 4x4 per thread, h1T (fp32) in LDS.
__global__ __launch_bounds__(THREADS) void k_gemm2(const __half* __restrict__ h1,
                                                   const float* __restrict__ W2,
                                                   const float* __restrict__ dinv,
                                                   __half* __restrict__ g2, int N) {
    __shared__ float hT[64 * 129];
    __shared__ float Wl[64 * 32];
    for (int i = threadIdx.x; i < 64 * 32; i += THREADS) Wl[i] = W2[i];
    int row0 = blockIdx.x * 128;
    int kq = threadIdx.x & 31;
    int rr = threadIdx.x >> 5;
#pragma unroll
    for (int it = 0; it < 16; ++it) {
        int r = rr + it * 8;
        int gr = row0 + r;
        __half2 v = __floats2half2_rn(0.f, 0.f);
        if (gr < N) v = ((const __half2*)(h1 + (size_t)gr * 64))[kq];
        float2 fv = __half22float2(v);
        hT[(2 * kq + 0) * 129 + r] = fv.x;
        hT[(2 * kq + 1) * 129 + r] = fv.y;
    }
    __syncthreads();
    int tx = threadIdx.x & 7;
    int ty = threadIdx.x >> 3;
    float acc[4][4] = {};
#pragma unroll 4
    for (int k = 0; k < 64; ++k) {
        float4 a = *(const float4*)&hT[k * 129 + ty * 4];
        float4 b = *(const float4*)&Wl[k * 32 + tx * 4];
        acc[0][0] = fmaf(a.x, b.x, acc[0][0]);
        acc[0][1] = fmaf(a.x, b.y, acc[0][1]);
        acc[0][2] = fmaf(a.x, b.z, acc[0][2]);
        acc[0][3] = fmaf(a.x, b.w, acc[0][3]);
        acc[1][0] = fmaf(a.y, b.x, acc[1][0]);
        acc[1][1] = fmaf(a.y, b.y, acc[1][1]);
        acc[1][2] = fmaf(a.y, b.z, acc[1][2]);
        acc[1][3] = fmaf(a.y, b.w, acc[1][3]);
        acc[2][0] = fmaf(a.z, b.x, acc[2][0]);
        acc[2][1] = fmaf(a.z, b.y, acc[2][1]);
        acc[2][2] = fmaf(a.z, b.z, acc[2][2]);
        acc[2][3] = fmaf(a.z, b.w, acc[2][3]);
        acc[3][0] = fmaf(a.w, b.x, acc[3][0]);
        acc[3][1] = fmaf(a.w, b.y, acc[3][1]);
        acc[3][2] = fmaf(a.w, b.z, acc[3][2]);
        acc[3][3] = fmaf(a.w, b.w, acc[3][3]);
    }
#pragma unroll
    for (int i = 0; i < 4; ++i) {
        int gr = row0 + ty * 4 + i;
        if (gr < N) {
            float dr = dinv[gr];
            Half4 o;
            o.a = __floats2half2_rn(acc[i][0] * dr, acc[i][1] * dr);
            o.b = __floats2half2_rn(acc[i][2] * dr, acc[i][3] * dr);
            *(Half4*)(g2 + (size_t)gr * 32 + tx * 4) = o;
        }
    }
}

// 16 lanes per node, lane f = half2 feature pair; 16-deep gather pipeline
__global__ __launch_bounds__(THREADS) void k_agg2(const int* __restrict__ rowptr,
                                                  const int* __restrict__ csr,
                                                  const __half* __restrict__ g2h,
                                                  const float* __restrict__ dinv,
                                                  const float* __restrict__ b2,
                                                  float* __restrict__ out, int N) {
    const __half2* g2 = (const __half2*)g2h;
    int v = (blockIdx.x * THREADS + threadIdx.x) >> 4;
    if (v >= N) return;
    int f = threadIdx.x & 15;
    int beg = rowptr[v], end = rowptr[v + 1];
    float2 s = __half22float2(g2[(size_t)v * 16 + f]);
    float sx = s.x, sy = s.y;
    int j = beg;
    for (; j + 16 <= end; j += 16) {
        int idx[16];
#pragma unroll
        for (int u = 0; u < 16; ++u) idx[u] = csr[j + u];
        __half2 a[16];
#pragma unroll
        for (int u = 0; u < 16; ++u) a[u] = g2[(size_t)idx[u] * 16 + f];
        float tx = 0.f, ty = 0.f;
#pragma unroll
        for (int u = 0; u < 16; ++u) {
            float2 fa = __half22float2(a[u]);
            tx += fa.x; ty += fa.y;
        }
        sx += tx; sy += ty;
    }
    if (j + 8 <= end) {
        int idx[8];
#pragma unroll
        for (int u = 0; u < 8; ++u) idx[u] = csr[j + u];
        __half2 a[8];
#pragma unroll
        for (int u = 0; u < 8; ++u) a[u] = g2[(size_t)idx[u] * 16 + f];
#pragma unroll
        for (int u = 0; u < 8; ++u) {
            float2 fa = __half22float2(a[u]);
            sx += fa.x; sy += fa.y;
        }
        j += 8;
    }
    for (; j < end; ++j) {
        float2 a = __half22float2(g2[(size_t)csr[j] * 16 + f]);
        sx += a.x; sy += a.y;
    }
    float dr = dinv[v];
    float2 o;
    o.x = fmaf(dr, sx, b2[2 * f + 0]);
    o.y = fmaf(dr, sy, b2[2 * f + 1]);
    ((float2*)out)[(size_t)v * 16 + f] = o;
}

extern "C" void kernel_launch(void* const* d_in, const int* in_sizes, int n_in,
                              void* d_out, int out_size, void* d_ws, size_t ws_size,
                              hipStream_t stream) {
    const float* x  = (const float*)d_in[0];
    const int* eidx = (const int*)d_in[1];
    const float* W1 = (const float*)d_in[2];
    const float* b1 = (const float*)d_in[3];
    const float* W2 = (const float*)d_in[4];
    const float* b2 = (const float*)d_in[5];
    float* out = (float*)d_out;

    const int N = in_sizes[0] / 128;   // 100000
    const int E = in_sizes[1] / 2;     // 3200000
    const int K = (N + NB - 1) / NB;   // 391
    const int C = (E + NCHUNK - 1) / NCHUNK;

    // ws layout (ints), no aliasing
    int* flag   = (int*)d_ws;                            // 64
    int* H      = flag + 64;                             // NCHUNK*400
    int* btot   = H + (size_t)NCHUNK * 400;              // 400
    int* base   = btot + 400;                            // 448
    unsigned int* packed = (unsigned int*)(base + 448);  // E
    int* csr    = (int*)(packed + E);                    // E
    int* rowptr = csr + E;                               // N+1 (100032)
    float* dinv = (float*)(rowptr + 100032);             // 100032
    __half* g1  = (__half*)(dinv + 100032);              // N*64 halfs
    __half* h1  = g1 + (size_t)N * 64;                   // N*64 halfs
    __half* g2  = h1 + (size_t)N * 64;                   // N*32 halfs

    k_detect<<<1, 64, 0, stream>>>(eidx, flag);
    k_hist<<<NCHUNK, HTHREADS, 0, stream>>>(eidx, flag, E, C, K, H);
    k_colscan<<<(K * 64 + THREADS - 1) / THREADS, THREADS, 0, stream>>>(H, btot, K, NCHUNK);
    k_basescan<<<1, 1024, 0, stream>>>(btot, base, K);
    k_passB<<<NCHUNK, HTHREADS, 0, stream>>>(eidx, flag, E, C, K, H, base, packed);
    k_passC<<<K, NB, 0, stream>>>(packed, base, K, N, csr, rowptr, dinv);
    k_gemm1<<<(N + 63) / 64, THREADS, 0, stream>>>(x, W1, dinv, g1, N);
    k_agg1<<<(N * 32 + THREADS - 1) / THREADS, THREADS, 0, stream>>>(rowptr, csr, g1, dinv, b1, h1, N);
    k_gemm2<<<(N + 127) / 128, THREADS, 0, stream>>>(h1, W2, dinv, g2, N);
    k_agg2<<<(N * 16 + THREADS - 1) / THREADS, THREADS, 0, stream>>>(rowptr, csr, g2, dinv, b2, out, N);
}

// Round 14
// 224.507 us; speedup vs baseline: 1.2513x; 1.0661x over previous
//
#include <hip/hip_runtime.h>
#include <hip/hip_fp16.h>

#define THREADS 256
#define HTHREADS 1024
#define NB 256           // nodes per bucket
#define KMAX 400         // >= ceil(N/NB)=391
#define NCHUNK 512       // edge chunks for bucket sort
#define NXCD 8

struct alignas(8) Half4 { __half2 a, b; };
typedef _Float16 half8 __attribute__((ext_vector_type(8)));
typedef float floatx4 __attribute__((ext_vector_type(4)));

// ---------------------------------------------------------------------------
// detect -> hist -> colscan -> basescan -> passB -> passC ->
// gemm1 (MFMA 16x16x32 f16, no LDS) -> agg1 (128B-row gather, 16-deep) ->
// gemm2 (MFMA, no LDS) -> agg2 (64B-row gather, 16-deep)
//
// R13 lessons: (1) agg1 pinned at 3.57 TB/s across ILP/split/occupancy
// changes -> random-gather MSHR*latency wall; stop pushing. (2) MFMA GEMM
// works (layouts verified by passing absmax). This round: MFMA gemm2 +
// XCD-aware chunk permutation (adjacent packed regions -> same XCD, since
// blockIdx round-robins XCDs) to cut passB's cross-XCD line bounce.
// packed edge = (src << 8) | (dst & 255); bucket = dst >> 8
// chunk perm: block b -> logical chunk (b&7)*(NCHUNK/8) + (b>>3)
// ---------------------------------------------------------------------------

__global__ void k_detect(const int* __restrict__ e32, int* __restrict__ flag) {
    if (blockIdx.x == 0 && threadIdx.x == 0) {
        int st = 2;
        for (int i = 0; i < 64; ++i)
            if (e32[2 * i + 1] != 0) { st = 1; break; }
        *flag = st;
    }
}

__global__ __launch_bounds__(HTHREADS) void k_hist(const int* __restrict__ eidx,
                                                   const int* __restrict__ flag,
                                                   int E, int C, int K,
                                                   int* __restrict__ H) {
    __shared__ int hl[KMAX];
    int st = *flag;
    int lc = (blockIdx.x & (NXCD - 1)) * (NCHUNK / NXCD) + (blockIdx.x >> 3);
    for (int i = threadIdx.x; i < K; i += HTHREADS) hl[i] = 0;
    __syncthreads();
    int s0 = lc * C;
    int s1 = min(s0 + C, E);
    for (int e = s0 + threadIdx.x; e < s1; e += HTHREADS) {
        int d = eidx[(size_t)(E + e) * st];
        atomicAdd(&hl[d >> 8], 1);
    }
    __syncthreads();
    for (int i = threadIdx.x; i < K; i += HTHREADS)
        H[(size_t)lc * K + i] = hl[i];
}

// wave per bucket: exclusive prefix of H[c][b] over c
__global__ __launch_bounds__(THREADS) void k_colscan(int* __restrict__ H,
                                                     int* __restrict__ btot,
                                                     int K, int nchunk) {
    int b = (blockIdx.x * THREADS + threadIdx.x) >> 6;
    if (b >= K) return;
    int lane = threadIdx.x & 63;
    int run = 0;
    for (int i = 0; i < nchunk; i += 64) {
        int c = i + lane;
        int v = H[(size_t)c * K + b];
        int xs = v;
#pragma unroll
        for (int off = 1; off < 64; off <<= 1) {
            int t = __shfl_up(xs, off, 64);
            if (lane >= off) xs += t;
        }
        H[(size_t)c * K + b] = run + (xs - v);
        run += __shfl(xs, 63, 64);
    }
    if (lane == 0) btot[b] = run;
}

// exclusive scan of K<=2048 bucket totals, single block
__global__ __launch_bounds__(1024) void k_basescan(const int* __restrict__ btot,
                                                   int* __restrict__ base, int K) {
    __shared__ int s0[2048], s1[2048];
    int t = threadIdx.x;
    for (int i = t; i < 2048; i += 1024) s0[i] = (i < K) ? btot[i] : 0;
    __syncthreads();
    int* src = s0; int* dst = s1;
    for (int off = 1; off < 2048; off <<= 1) {
        for (int i = t; i < 2048; i += 1024)
            dst[i] = src[i] + (i >= off ? src[i - off] : 0);
        __syncthreads();
        int* tmp = src; src = dst; dst = tmp;
    }
    for (int i = t; i < 2048; i += 1024)
        if (i < K) base[i] = (i == 0) ? 0 : src[i - 1];
    if (t == 0) base[K] = src[K - 1];
}

__global__ __launch_bounds__(HTHREADS) void k_passB(const int* __restrict__ eidx,
                                                    const int* __restrict__ flag,
                                                    int E, int C, int K,
                                                    const int* __restrict__ H,
                                                    const int* __restrict__ base,
                                                    unsigned int* __restrict__ packed) {
    __shared__ int cur[KMAX];
    int st = *flag;
    int lc = (blockIdx.x & (NXCD - 1)) * (NCHUNK / NXCD) + (blockIdx.x >> 3);
    for (int i = threadIdx.x; i < K; i += HTHREADS)
        cur[i] = base[i] + H[(size_t)lc * K + i];
    __syncthreads();
    int s0 = lc * C;
    int s1 = min(s0 + C, E);
    for (int e = s0 + threadIdx.x; e < s1; e += HTHREADS) {
        int s = eidx[(size_t)e * st];
        int d = eidx[(size_t)(E + e) * st];
        int pos = atomicAdd(&cur[d >> 8], 1);
        packed[pos] = ((unsigned)s << 8) | (unsigned)(d & 255);
    }
}

// per-bucket counting sort: packed -> csr (src by node), rowptr, dinv
__global__ __launch_bounds__(NB) void k_passC(const unsigned int* __restrict__ pk,
                                              const int* __restrict__ base,
                                              int K, int N,
                                              int* __restrict__ csr,
                                              int* __restrict__ rowptr,
                                              float* __restrict__ dinv) {
    __shared__ int cnt[NB];
    __shared__ int scn[NB];
    __shared__ int cur[NB];
    int b = blockIdx.x;
    int b0 = base[b], b1e = base[b + 1];
    int t = threadIdx.x;
    cnt[t] = 0;
    __syncthreads();
    for (int e = b0 + t; e < b1e; e += NB)
        atomicAdd(&cnt[pk[e] & 255u], 1);
    __syncthreads();
    int val = cnt[t];
    scn[t] = val;
    __syncthreads();
    for (int off = 1; off < NB; off <<= 1) {
        int tmp = (t >= off) ? scn[t - off] : 0;
        __syncthreads();
        scn[t] += tmp;
        __syncthreads();
    }
    int excl = b0 + scn[t] - val;
    cur[t] = excl;
    int v = b * NB + t;
    if (v < N) {
        rowptr[v] = excl;
        dinv[v] = rsqrtf((float)val + 1.0f);
    }
    if (b == K - 1 && t == 0) rowptr[N] = b1e;
    __syncthreads();
    for (int e = b0 + t; e < b1e; e += NB) {
        unsigned p = pk[e];
        int pos = atomicAdd(&cur[p & 255u], 1);
        csr[pos] = (int)(p >> 8);
    }
}

// MFMA GEMM1: wave computes 16 rows x 64 cols; block = 4 waves = 64 rows.
__global__ __launch_bounds__(THREADS) void k_gemm1(const float* __restrict__ x,
                                                   const float* __restrict__ W1,
                                                   const float* __restrict__ dinv,
                                                   __half* __restrict__ g1, int N) {
    int wid = threadIdx.x >> 6;
    int lane = threadIdx.x & 63;
    int r0 = blockIdx.x * 64 + wid * 16;
    int lrow = lane & 15;
    int khi = lane >> 4;              // 0..3
    int arow = min(r0 + lrow, N - 1);

    half8 a[4];
    const float* xr = x + (size_t)arow * 128 + khi * 8;
#pragma unroll
    for (int kt = 0; kt < 4; ++kt) {
        float4 v0 = *(const float4*)(xr + kt * 32);
        float4 v1 = *(const float4*)(xr + kt * 32 + 4);
        half8 h;
        h[0] = (_Float16)v0.x; h[1] = (_Float16)v0.y;
        h[2] = (_Float16)v0.z; h[3] = (_Float16)v0.w;
        h[4] = (_Float16)v1.x; h[5] = (_Float16)v1.y;
        h[6] = (_Float16)v1.z; h[7] = (_Float16)v1.w;
        a[kt] = h;
    }

    floatx4 acc[4] = {};
#pragma unroll
    for (int ct = 0; ct < 4; ++ct) {
#pragma unroll
        for (int kt = 0; kt < 4; ++kt) {
            const float* wp = W1 + (size_t)(kt * 32 + khi * 8) * 64 + ct * 16 + lrow;
            half8 b;
#pragma unroll
            for (int j = 0; j < 8; ++j) b[j] = (_Float16)wp[(size_t)j * 64];
            acc[ct] = __builtin_amdgcn_mfma_f32_16x16x32_f16(a[kt], b, acc[ct], 0, 0, 0);
        }
    }

#pragma unroll
    for (int reg = 0; reg < 4; ++reg) {
        int r = r0 + khi * 4 + reg;
        if (r < N) {
            float dr = dinv[r];
#pragma unroll
            for (int ct = 0; ct < 4; ++ct)
                g1[(size_t)r * 64 + ct * 16 + lrow] = __float2half(acc[ct][reg] * dr);
        }
    }
}

// 32 lanes per node, lane f = half2 feature pair; 16-deep gather pipeline
__global__ __launch_bounds__(THREADS) void k_agg1(const int* __restrict__ rowptr,
                                                  const int* __restrict__ csr,
                                                  const __half* __restrict__ g1h,
                                                  const float* __restrict__ dinv,
                                                  const float* __restrict__ b1,
                                                  __half* __restrict__ h1h, int N) {
    const __half2* g1 = (const __half2*)g1h;
    __half2* h1 = (__half2*)h1h;
    int v = (blockIdx.x * THREADS + threadIdx.x) >> 5;
    if (v >= N) return;
    int f = threadIdx.x & 31;
    int beg = rowptr[v], end = rowptr[v + 1];
    float2 s = __half22float2(g1[(size_t)v * 32 + f]);
    float sx = s.x, sy = s.y;
    int j = beg;
    for (; j + 16 <= end; j += 16) {
        int idx[16];
#pragma unroll
        for (int u = 0; u < 16; ++u) idx[u] = csr[j + u];
        __half2 a[16];
#pragma unroll
        for (int u = 0; u < 16; ++u) a[u] = g1[(size_t)idx[u] * 32 + f];
        float tx = 0.f, ty = 0.f;
#pragma unroll
        for (int u = 0; u < 16; ++u) {
            float2 fa = __half22float2(a[u]);
            tx += fa.x; ty += fa.y;
        }
        sx += tx; sy += ty;
    }
    if (j + 8 <= end) {
        int idx[8];
#pragma unroll
        for (int u = 0; u < 8; ++u) idx[u] = csr[j + u];
        __half2 a[8];
#pragma unroll
        for (int u = 0; u < 8; ++u) a[u] = g1[(size_t)idx[u] * 32 + f];
#pragma unroll
        for (int u = 0; u < 8; ++u) {
            float2 fa = __half22float2(a[u]);
            sx += fa.x; sy += fa.y;
        }
        j += 8;
    }
    for (; j < end; ++j) {
        float2 a = __half22float2(g1[(size_t)csr[j] * 32 + f]);
        sx += a.x; sy += a.y;
    }
    float dr = dinv[v];
    float h0 = fmaxf(fmaf(dr, sx, b1[2 * f + 0]), 0.0f);
    float h1v = fmaxf(fmaf(dr, sy, b1[2 * f + 1]), 0.0f);
    h1[(size_t)v * 32 + f] = __floats2half2_rn(h0, h1v);
}

// MFMA GEMM2: wave computes 16 rows x 32 cols; block = 4 waves = 64 rows.
// g2[r][c] = half((h1[r,:] @ W2[:,c]) * dinv[r]); h1 already fp16.
__global__ __launch_bounds__(THREADS) void k_gemm2(const __half* __restrict__ h1,
                                                   const float* __restrict__ W2,
                                                   const float* __restrict__ dinv,
                                                   __half* __restrict__ g2, int N) {
    int wid = threadIdx.x >> 6;
    int lane = threadIdx.x & 63;
    int r0 = blockIdx.x * 64 + wid * 16;
    int lrow = lane & 15;
    int khi = lane >> 4;              // 0..3
    int arow = min(r0 + lrow, N - 1);

    // A frags: k-tiles kt=0,1; lane holds h1[arow][kt*32 + khi*8 .. +7] (16B)
    half8 a[2];
    const __half* hr = h1 + (size_t)arow * 64 + khi * 8;
#pragma unroll
    for (int kt = 0; kt < 2; ++kt)
        a[kt] = *(const half8*)(hr + kt * 32);

    floatx4 acc[2] = {};
#pragma unroll
    for (int ct = 0; ct < 2; ++ct) {
#pragma unroll
        for (int kt = 0; kt < 2; ++kt) {
            const float* wp = W2 + (size_t)(kt * 32 + khi * 8) * 32 + ct * 16 + lrow;
            half8 b;
#pragma unroll
            for (int j = 0; j < 8; ++j) b[j] = (_Float16)wp[(size_t)j * 32];
            acc[ct] = __builtin_amdgcn_mfma_f32_16x16x32_f16(a[kt], b, acc[ct], 0, 0, 0);
        }
    }

#pragma unroll
    for (int reg = 0; reg < 4; ++reg) {
        int r = r0 + khi * 4 + reg;
        if (r < N) {
            float dr = dinv[r];
#pragma unroll
            for (int ct = 0; ct < 2; ++ct)
                g2[(size_t)r * 32 + ct * 16 + lrow] = __float2half(acc[ct][reg] * dr);
        }
    }
}

// 16 lanes per node, lane f = half2 feature pair; 16-deep gather pipeline
__global__ __launch_bounds__(THREADS) void k_agg2(const int* __restrict__ rowptr,
                                                  const int* __restrict__ csr,
                                                  const __half* __restrict__ g2h,
                                                  const float* __restrict__ dinv,
                                                  const float* __restrict__ b2,
                                                  float* __restrict__ out, int N) {
    const __half2* g2 = (const __half2*)g2h;
    int v = (blockIdx.x * THREADS + threadIdx.x) >> 4;
    if (v >= N) return;
    int f = threadIdx.x & 15;
    int beg = rowptr[v], end = rowptr[v + 1];
    float2 s = __half22float2(g2[(size_t)v * 16 + f]);
    float sx = s.x, sy = s.y;
    int j = beg;
    for (; j + 16 <= end; j += 16) {
        int idx[16];
#pragma unroll
        for (int u = 0; u < 16; ++u) idx[u] = csr[j + u];
        __half2 a[16];
#pragma unroll
        for (int u = 0; u < 16; ++u) a[u] = g2[(size_t)idx[u] * 16 + f];
        float tx = 0.f, ty = 0.f;
#pragma unroll
        for (int u = 0; u < 16; ++u) {
            float2 fa = __half22float2(a[u]);
            tx += fa.x; ty += fa.y;
        }
        sx += tx; sy += ty;
    }
    if (j + 8 <= end) {
        int idx[8];
#pragma unroll
        for (int u = 0; u < 8; ++u) idx[u] = csr[j + u];
        __half2 a[8];
#pragma unroll
        for (int u = 0; u < 8; ++u) a[u] = g2[(size_t)idx[u] * 16 + f];
#pragma unroll
        for (int u = 0; u < 8; ++u) {
            float2 fa = __half22float2(a[u]);
            sx += fa.x; sy += fa.y;
        }
        j += 8;
    }
    for (; j < end; ++j) {
        float2 a = __half22float2(g2[(size_t)csr[j] * 16 + f]);
        sx += a.x; sy += a.y;
    }
    float dr = dinv[v];
    float2 o;
    o.x = fmaf(dr, sx, b2[2 * f + 0]);
    o.y = fmaf(dr, sy, b2[2 * f + 1]);
    ((float2*)out)[(size_t)v * 16 + f] = o;
}

extern "C" void kernel_launch(void* const* d_in, const int* in_sizes, int n_in,
                              void* d_out, int out_size, void* d_ws, size_t ws_size,
                              hipStream_t stream) {
    const float* x  = (const float*)d_in[0];
    const int* eidx = (const int*)d_in[1];
    const float* W1 = (const float*)d_in[2];
    const float* b1 = (const float*)d_in[3];
    const float* W2 = (const float*)d_in[4];
    const float* b2 = (const float*)d_in[5];
    float* out = (float*)d_out;

    const int N = in_sizes[0] / 128;   // 100000
    const int E = in_sizes[1] / 2;     // 3200000
    const int K = (N + NB - 1) / NB;   // 391
    const int C = (E + NCHUNK - 1) / NCHUNK;

    // ws layout (ints), no aliasing
    int* flag   = (int*)d_ws;                            // 64
    int* H      = flag + 64;                             // NCHUNK*400
    int* btot   = H + (size_t)NCHUNK * 400;              // 400
    int* base   = btot + 400;                            // 448
    unsigned int* packed = (unsigned int*)(base + 448);  // E
    int* csr    = (int*)(packed + E);                    // E
    int* rowptr = csr + E;                               // N+1 (100032)
    float* dinv = (float*)(rowptr + 100032);             // 100032
    __half* g1  = (__half*)(dinv + 100032);              // N*64 halfs
    __half* h1  = g1 + (size_t)N * 64;                   // N*64 halfs
    __half* g2  = h1 + (size_t)N * 64;                   // N*32 halfs

    k_detect<<<1, 64, 0, stream>>>(eidx, flag);
    k_hist<<<NCHUNK, HTHREADS, 0, stream>>>(eidx, flag, E, C, K, H);
    k_colscan<<<(K * 64 + THREADS - 1) / THREADS, THREADS, 0, stream>>>(H, btot, K, NCHUNK);
    k_basescan<<<1, 1024, 0, stream>>>(btot, base, K);
    k_passB<<<NCHUNK, HTHREADS, 0, stream>>>(eidx, flag, E, C, K, H, base, packed);
    k_passC<<<K, NB, 0, stream>>>(packed, base, K, N, csr, rowptr, dinv);
    k_gemm1<<<(N + 63) / 64, THREADS, 0, stream>>>(x, W1, dinv, g1, N);
    k_agg1<<<(N * 32 + THREADS - 1) / THREADS, THREADS, 0, stream>>>(rowptr, csr, g1, dinv, b1, h1, N);
    k_gemm2<<<(N + 63) / 64, THREADS, 0, stream>>>(h1, W2, dinv, g2, N);
    k_agg2<<<(N * 16 + THREADS - 1) / THREADS, THREADS, 0, stream>>>(rowptr, csr, g2, dinv, b2, out, N);
}